// Round 5
// baseline (870.323 us; speedup 1.0000x reference)
//
#include <hip/hip_runtime.h>

// GAT layer on MI355X. N=50000, E=800000 (+N self loops), DIN=256, DOUT=128, H=8.
//
//  r11: deleted the CSR entirely. fine_scatter (~38us) + aggregate (~40us)
//  existed only to sort edges per dst; instead, one block per 128-dst-node
//  bucket accumulates the UNNORMALIZED numerator num[128][128] (f32, 64KB)
//  and denominator den[128][8] in LDS via ds_add_f32 over the bucket's
//  unsorted pair list, then normalizes + injects self-loops in the epilogue.
//  LDS atomics are CU-local (r8 showed device-scope atomics cause HBM RMW
//  traffic; LDS ones don't). Summation order changes only fp32 rounding.
//
//  K1 conv_w      : W_bf = bf16(W_trans); zeroes per-bucket counters
//  K2 bp          : bucket_pass, 391 buckets of 128 dst nodes, 2KB-class LDS,
//                   full occupancy (packed u32 = src<<8 | dst&127)
//  K3 gemm        : h_bf = bf16(x @ W^T), 16x16x32 MFMA, W staged in 64KiB
//                   LDS in fragment order (r9 core, epilogue-clean)
//  K4 node_scores : a_src/a_dst = h_bf . W_att halves, thread per (v,head)
//  K5 bucket_agg  : one block (512 thr) per bucket: LDS num/den accumulate
//                   (d-XOR-swizzled cols), self-loop + normalize epilogue

constexpr int DIN  = 256;
constexpr int DOUT = 128;
constexpr int H    = 8;
constexpr int BKT  = 128;   // dst nodes per bucket
constexpr int CAP  = 2560;  // pair_buf slots per bucket (mean 2048, +11 sigma)
constexpr int CHUNK = 2048; // edges per bucket_pass block
constexpr int MAXNB = 512;  // static LDS sizing for bp hist (nb=391 actual)

typedef __attribute__((ext_vector_type(8))) short bf16x8;
typedef __attribute__((ext_vector_type(4))) float f32x4;

__device__ __forceinline__ float lrelu(float s) { return s >= 0.0f ? s : 0.2f * s; }

__device__ __forceinline__ unsigned short f2bf(float f) {  // RNE
  unsigned u = __float_as_uint(f);
  u += 0x7FFF + ((u >> 16) & 1);
  return (unsigned short)(u >> 16);
}
__device__ __forceinline__ float bflo(unsigned u) { return __uint_as_float(u << 16); }
__device__ __forceinline__ float bfhi(unsigned u) { return __uint_as_float(u & 0xFFFF0000u); }

// ---------------- K1: W -> bf16 (+ zero bucket counters) ----------------
__global__ void conv_w(const float* __restrict__ W, unsigned short* __restrict__ Wbf,
                       int n, int* __restrict__ bcount, int nb) {
  int i = blockIdx.x * blockDim.x + threadIdx.x;
  if (i < n) Wbf[i] = f2bf(W[i]);
  if (i < nb) bcount[i] = 0;
}

// ---------------- K2: bucket_pass (128-node buckets) ----------------
__global__ __launch_bounds__(256) void bp(const int* __restrict__ ei,
                                          int* __restrict__ bcount,
                                          unsigned* __restrict__ pair_buf,
                                          int E, int nb) {
  __shared__ int hist[MAXNB];
  __shared__ int gbase[MAXNB];
  int c0 = blockIdx.x * CHUNK;
  for (int i = threadIdx.x; i < nb; i += 256) hist[i] = 0;
  __syncthreads();
  int dcache[8];
#pragma unroll
  for (int q = 0; q < 8; ++q) {
    int e = c0 + q * 256 + threadIdx.x;
    dcache[q] = (e < E) ? ei[E + e] : -1;
    if (dcache[q] >= 0) atomicAdd(&hist[dcache[q] >> 7], 1);
  }
  __syncthreads();
  for (int i = threadIdx.x; i < nb; i += 256) {
    int c = hist[i];
    gbase[i] = c ? atomicAdd(&bcount[i], c) : 0;
  }
  __syncthreads();
  for (int i = threadIdx.x; i < nb; i += 256) hist[i] = 0;  // reuse as rank cursor
  __syncthreads();
  int scache[8];
#pragma unroll
  for (int q = 0; q < 8; ++q) {  // prefetch src indices (independent loads)
    int e = c0 + q * 256 + threadIdx.x;
    scache[q] = (dcache[q] >= 0) ? ei[e] : 0;
  }
#pragma unroll
  for (int q = 0; q < 8; ++q) {
    if (dcache[q] >= 0) {
      int bk = dcache[q] >> 7;
      int r = atomicAdd(&hist[bk], 1);
      pair_buf[bk * CAP + gbase[bk] + r] =
          ((unsigned)scache[q] << 8) | (unsigned)(dcache[q] & 127);
    }
  }
}

// ---------------- K3: GEMM ----------------
// wave: 32 rows x 128 cols. A-frag lane(mr,kg) holds A[m0+mt*16+mr][ks*32+kg*8..+8);
// C/D: col = t*16+mr, row = m0+mt*16+kg*4+r.
// B fragments from LDS (fragment-ordered stage of Wbf, 64 KiB).
__global__ __launch_bounds__(256, 2) void gemm(const float* __restrict__ x,
                                               const unsigned short* __restrict__ Wbf,
                                               unsigned short* __restrict__ hbf,
                                               int N) {
  __shared__ __align__(16) unsigned short Wlds[DOUT * DIN];  // 64 KiB
  // Stage W in fragment order: chunk c = (t*8+ks)*64 + L holds
  // Wbf[(t*16 + (L&15))*DIN + ks*32 + (L>>4)*8 .. +8).
  {
    const int tid = threadIdx.x;
#pragma unroll
    for (int i = 0; i < 16; ++i) {
      int c = i * 256 + tid;                 // chunk 0..4095
      int t = c >> 9, ks = (c >> 6) & 7, L = c & 63;
      const unsigned short* gp = Wbf + ((t * 16 + (L & 15)) * DIN + ks * 32 + (L >> 4) * 8);
      *(bf16x8*)&Wlds[c * 8] = *(const bf16x8*)gp;
    }
  }
  __syncthreads();
  int wid = blockIdx.x * 4 + (threadIdx.x >> 6);
  int m0 = wid * 32;
  if (m0 >= N) return;
  int lane = threadIdx.x & 63;
  int mr = lane & 15, kg = lane >> 4;
  int r0 = m0 + mr;       if (r0 >= N) r0 = N - 1;  // clamp (stores guarded)
  int r1 = m0 + 16 + mr;  if (r1 >= N) r1 = N - 1;
  const float* xr0 = x + (size_t)r0 * DIN + kg * 8;
  const float* xr1 = x + (size_t)r1 * DIN + kg * 8;
  const unsigned short* fb = Wlds + lane * 8;  // lane's fragment base

  f32x4 acc[2][8];
#pragma unroll
  for (int mt = 0; mt < 2; ++mt)
#pragma unroll
    for (int t = 0; t < 8; ++t) acc[mt][t] = (f32x4){0.f, 0.f, 0.f, 0.f};

  float4 p00 = *(const float4*)xr0, p01 = *(const float4*)(xr0 + 4);
  float4 p10 = *(const float4*)xr1, p11 = *(const float4*)(xr1 + 4);
#pragma unroll
  for (int ks = 0; ks < 8; ++ks) {
    bf16x8 a0, a1;
    a0[0] = (short)f2bf(p00.x); a0[1] = (short)f2bf(p00.y);
    a0[2] = (short)f2bf(p00.z); a0[3] = (short)f2bf(p00.w);
    a0[4] = (short)f2bf(p01.x); a0[5] = (short)f2bf(p01.y);
    a0[6] = (short)f2bf(p01.z); a0[7] = (short)f2bf(p01.w);
    a1[0] = (short)f2bf(p10.x); a1[1] = (short)f2bf(p10.y);
    a1[2] = (short)f2bf(p10.z); a1[3] = (short)f2bf(p10.w);
    a1[4] = (short)f2bf(p11.x); a1[5] = (short)f2bf(p11.y);
    a1[6] = (short)f2bf(p11.z); a1[7] = (short)f2bf(p11.w);
    if (ks < 7) {  // prefetch next ks while MFMAs run
      p00 = *(const float4*)(xr0 + (ks + 1) * 32);
      p01 = *(const float4*)(xr0 + (ks + 1) * 32 + 4);
      p10 = *(const float4*)(xr1 + (ks + 1) * 32);
      p11 = *(const float4*)(xr1 + (ks + 1) * 32 + 4);
    }
#pragma unroll
    for (int t = 0; t < 8; ++t) {
      bf16x8 b = *(const bf16x8*)(fb + ((t * 8 + ks) << 9));  // imm offset
      acc[0][t] = __builtin_amdgcn_mfma_f32_16x16x32_bf16(a0, b, acc[0][t], 0, 0, 0);
      acc[1][t] = __builtin_amdgcn_mfma_f32_16x16x32_bf16(a1, b, acc[1][t], 0, 0, 0);
    }
  }
#pragma unroll
  for (int mt = 0; mt < 2; ++mt)
#pragma unroll
    for (int t = 0; t < 8; ++t)
#pragma unroll
      for (int r = 0; r < 4; ++r) {
        int row = m0 + mt * 16 + kg * 4 + r;
        if (row < N) hbf[(size_t)row * DOUT + t * 16 + mr] = f2bf(acc[mt][t][r]);
      }
}

// ---------------- K4: node scores ----------------
__global__ __launch_bounds__(256) void node_scores(const unsigned short* __restrict__ hbf,
                                                   const float* __restrict__ Wa,
                                                   float* __restrict__ a_src,
                                                   float* __restrict__ a_dst,
                                                   int NH) {
  int idx = blockIdx.x * 256 + threadIdx.x;
  if (idx >= NH) return;
  int v = idx >> 3, hh = idx & 7;
  const unsigned short* hp = hbf + (size_t)v * DOUT + hh * 16;
  uint4 p0 = *(const uint4*)hp;
  uint4 p1 = *(const uint4*)(hp + 8);
  float hv[16];
  hv[0] = bflo(p0.x); hv[1] = bfhi(p0.x); hv[2] = bflo(p0.y); hv[3] = bfhi(p0.y);
  hv[4] = bflo(p0.z); hv[5] = bfhi(p0.z); hv[6] = bflo(p0.w); hv[7] = bfhi(p0.w);
  hv[8] = bflo(p1.x); hv[9] = bfhi(p1.x); hv[10] = bflo(p1.y); hv[11] = bfhi(p1.y);
  hv[12] = bflo(p1.z); hv[13] = bfhi(p1.z); hv[14] = bflo(p1.w); hv[15] = bfhi(p1.w);
  float s1 = 0.f, s2 = 0.f;
#pragma unroll
  for (int d = 0; d < 16; ++d) {
    s1 += hv[d] * Wa[d];
    s2 += hv[d] * Wa[16 + d];
  }
  a_src[idx] = s1;
  a_dst[idx] = s2;
}

// ---------------- K5: bucketed aggregation, no CSR ----------------
// One block per 128-dst-node bucket. 16-lane group per edge; lane sl covers
// cols [sl*8, sl*8+8) (one uint4 of the hbf row); head = sl>>1.
// num cols are XOR-swizzled by dst (c ^ ((d&7)<<2)) so concurrent edges'
// ds_add_f32 spread across banks. Epilogue injects self-loop + normalizes.
__global__ __launch_bounds__(512, 4) void bucket_agg(const unsigned* __restrict__ pair_buf,
                                                     const int* __restrict__ bcount,
                                                     const unsigned short* __restrict__ hbf,
                                                     const float* __restrict__ a_src,
                                                     const float* __restrict__ a_dst,
                                                     const float* __restrict__ b_att,
                                                     float* __restrict__ out, int N) {
  __shared__ float num[BKT][DOUT];  // 64 KB (swizzled cols)
  __shared__ float den[BKT][H];     // 4 KB
  __shared__ float adL[BKT][H];     // 4 KB
  const int t = threadIdx.x;
  const int B = blockIdx.x;
  const int v0 = B * BKT;
  for (int i = t; i < BKT * DOUT; i += 512) ((float*)num)[i] = 0.f;
  for (int i = t; i < BKT * H; i += 512) {
    ((float*)den)[i] = 0.f;
    int v = v0 + (i >> 3);
    ((float*)adL)[i] = (v < N) ? a_dst[(size_t)v * H + (i & 7)] : 0.f;
  }
  __syncthreads();
  const float bb = b_att[0];
  const int cntE = bcount[B];
  const unsigned* reg = pair_buf + (size_t)B * CAP;
  const int grp = t >> 4;   // 32 edge-groups
  const int sl = t & 15;
  const int head = sl >> 1;
  unsigned p = (grp < cntE) ? reg[grp] : 0u;
  for (int i = grp; i < cntE; i += 32) {
    unsigned pn = (i + 32 < cntE) ? reg[i + 32] : 0u;  // prefetch next
    int src = p >> 8;
    int d = p & 127;
    float e = __expf(lrelu(a_src[(size_t)src * H + head] + adL[d][head] + bb));
    uint4 u = *(const uint4*)(hbf + (size_t)src * DOUT + sl * 8);
    float* row = &num[d][0];
    int xr = (d & 7) << 2;
    int c = sl * 8;
    atomicAdd(&row[(c + 0) ^ xr], e * bflo(u.x));
    atomicAdd(&row[(c + 1) ^ xr], e * bfhi(u.x));
    atomicAdd(&row[(c + 2) ^ xr], e * bflo(u.y));
    atomicAdd(&row[(c + 3) ^ xr], e * bfhi(u.y));
    atomicAdd(&row[(c + 4) ^ xr], e * bflo(u.z));
    atomicAdd(&row[(c + 5) ^ xr], e * bfhi(u.z));
    atomicAdd(&row[(c + 6) ^ xr], e * bflo(u.w));
    atomicAdd(&row[(c + 7) ^ xr], e * bfhi(u.w));
    if ((sl & 1) == 0) atomicAdd(&den[d][head], e);
    p = pn;
  }
  __syncthreads();
  // ---- epilogue: self loop + normalize + store (group per node) ----
  for (int nd = grp; nd < BKT; nd += 32) {
    int v = v0 + nd;
    if (v >= N) continue;  // uniform per group
    float es = __expf(lrelu(a_src[(size_t)v * H + head] + adL[nd][head] + bb));
    float inv = 1.0f / (den[nd][head] + es);
    int xr = (nd & 7) << 2;
    int c = sl * 8;
    uint4 u = *(const uint4*)(hbf + (size_t)v * DOUT + c);
    float h0 = bflo(u.x), h1 = bfhi(u.x), h2 = bflo(u.y), h3 = bfhi(u.y);
    float h4 = bflo(u.z), h5 = bfhi(u.z), h6 = bflo(u.w), h7 = bfhi(u.w);
    float4 o0 = make_float4((num[nd][(c + 0) ^ xr] + es * h0) * inv,
                            (num[nd][(c + 1) ^ xr] + es * h1) * inv,
                            (num[nd][(c + 2) ^ xr] + es * h2) * inv,
                            (num[nd][(c + 3) ^ xr] + es * h3) * inv);
    float4 o1 = make_float4((num[nd][(c + 4) ^ xr] + es * h4) * inv,
                            (num[nd][(c + 5) ^ xr] + es * h5) * inv,
                            (num[nd][(c + 6) ^ xr] + es * h6) * inv,
                            (num[nd][(c + 7) ^ xr] + es * h7) * inv);
    *(float4*)&out[(size_t)v * DOUT + c] = o0;
    *(float4*)&out[(size_t)v * DOUT + c + 4] = o1;
  }
}

extern "C" void kernel_launch(void* const* d_in, const int* in_sizes, int n_in,
                              void* d_out, int out_size, void* d_ws, size_t ws_size,
                              hipStream_t stream) {
  const float* x     = (const float*)d_in[0];
  const float* W     = (const float*)d_in[1];
  const float* Wa    = (const float*)d_in[2];
  const float* b_att = (const float*)d_in[3];
  const int*   ei    = (const int*)d_in[4];
  const int N  = in_sizes[0] / DIN;
  const int E  = in_sizes[4] / 2;
  const int NB = (N + BKT - 1) / BKT;  // 391 buckets of 128 dst nodes
  float* out = (float*)d_out;

  char* p = (char*)d_ws;
  auto take = [&p](size_t bytes) {
    uintptr_t u = ((uintptr_t)p + 15) & ~(uintptr_t)15;
    p = (char*)(u + bytes);
    return (void*)u;
  };
  unsigned short* hbf = (unsigned short*)take((size_t)N * DOUT * 2);
  unsigned short* Wbf = (unsigned short*)take((size_t)DOUT * DIN * 2);
  float* a_src        = (float*)take((size_t)N * H * 4);
  float* a_dst        = (float*)take((size_t)N * H * 4);
  int* bcount         = (int*)take((size_t)NB * 4);
  unsigned* pair_buf  = (unsigned*)take((size_t)NB * CAP * 4);

  dim3 b256(256);
  const int cw_blocks   = (DOUT * DIN + 255) / 256;       // 128 (covers nb zeroing)
  const int bp_blocks   = (E + CHUNK - 1) / CHUNK;        // 391
  const int gemm_blocks = ((N + 31) / 32 + 3) / 4;        // 391 (4 waves x 32 rows)
  const int ns_blocks   = (N * H + 255) / 256;            // 1563

  conv_w<<<dim3(cw_blocks), b256, 0, stream>>>(W, Wbf, DOUT * DIN, bcount, NB);
  bp<<<dim3(bp_blocks), b256, 0, stream>>>(ei, bcount, pair_buf, E, NB);
  gemm<<<dim3(gemm_blocks), b256, 0, stream>>>(x, Wbf, hbf, N);
  node_scores<<<dim3(ns_blocks), b256, 0, stream>>>(hbf, Wa, a_src, a_dst, N * H);
  bucket_agg<<<dim3(NB), dim3(512), 0, stream>>>(pair_buf, bcount, hbf, a_src, a_dst,
                                                 b_att, out, N);
}

// Round 7
// 176.225 us; speedup vs baseline: 4.9387x; 4.9387x over previous
//
#include <hip/hip_runtime.h>

// GAT layer on MI355X. N=50000, E=800000 (+N self loops), DIN=256, DOUT=128, H=8.
//
//  r12: r11's 100M-LDS-atomic bucket_agg (744us, 4-way-bank-conflicted
//  ds_add_f32) reverted. Instead fine_scatter+aggregate are FUSED into one
//  block-local kernel: 391 buckets x 128 dst nodes; hist+scan+scatter build a
//  5KB LDS edge list (ushort src), then 16-lane groups aggregate per dst with
//  REGISTER accumulators (den is per-lane-private by head -> zero shuffles,
//  zero LDS atomics in the hot loop). Deletes the src_sorted/offsets global
//  round-trip and the 196-block occupancy hole.
//
//  K1 conv_w      : W_bf = bf16(W_trans); zeroes per-bucket counters
//  K2 bp          : bucket_pass, 391 buckets of 128 dst nodes, full occupancy
//                   (packed u32 = src<<8 | dst&127)
//  K3 gemm        : h_bf = bf16(x @ W^T), 16x16x32 MFMA, W staged in 64KiB
//                   LDS in fragment order (r9 core)
//  K4 node_scores : a_src/a_dst = h_bf . W_att halves, thread per (v,head)
//  K5 agg         : per bucket: LDS hist+scan+scatter -> slist; group per dst
//                   gathers hbf rows + a_src, accumulates in registers,
//                   self-loop + normalize epilogue

constexpr int DIN  = 256;
constexpr int DOUT = 128;
constexpr int H    = 8;
constexpr int BKT  = 128;   // dst nodes per bucket
constexpr int CAP  = 2560;  // pair_buf slots per bucket (mean 2048, +11 sigma)
constexpr int CHUNK = 2048; // edges per bucket_pass block
constexpr int MAXNB = 512;  // static LDS sizing for bp hist (nb=391 actual)

typedef __attribute__((ext_vector_type(8))) short bf16x8;
typedef __attribute__((ext_vector_type(4))) float f32x4;

__device__ __forceinline__ float lrelu(float s) { return s >= 0.0f ? s : 0.2f * s; }

__device__ __forceinline__ unsigned short f2bf(float f) {  // RNE
  unsigned u = __float_as_uint(f);
  u += 0x7FFF + ((u >> 16) & 1);
  return (unsigned short)(u >> 16);
}
__device__ __forceinline__ float bflo(unsigned u) { return __uint_as_float(u << 16); }
__device__ __forceinline__ float bfhi(unsigned u) { return __uint_as_float(u & 0xFFFF0000u); }

__device__ __forceinline__ int wave_incl_scan(int v, int lane) {
#pragma unroll
  for (int d = 1; d < 64; d <<= 1) {
    int t = __shfl_up(v, d, 64);
    if (lane >= d) v += t;
  }
  return v;
}

// ---------------- K1: W -> bf16 (+ zero bucket counters) ----------------
__global__ void conv_w(const float* __restrict__ W, unsigned short* __restrict__ Wbf,
                       int n, int* __restrict__ bcount, int nb) {
  int i = blockIdx.x * blockDim.x + threadIdx.x;
  if (i < n) Wbf[i] = f2bf(W[i]);
  if (i < nb) bcount[i] = 0;
}

// ---------------- K2: bucket_pass (128-node buckets) ----------------
__global__ __launch_bounds__(256) void bp(const int* __restrict__ ei,
                                          int* __restrict__ bcount,
                                          unsigned* __restrict__ pair_buf,
                                          int E, int nb) {
  __shared__ int hist[MAXNB];
  __shared__ int gbase[MAXNB];
  int c0 = blockIdx.x * CHUNK;
  for (int i = threadIdx.x; i < nb; i += 256) hist[i] = 0;
  __syncthreads();
  int dcache[8];
#pragma unroll
  for (int q = 0; q < 8; ++q) {
    int e = c0 + q * 256 + threadIdx.x;
    dcache[q] = (e < E) ? ei[E + e] : -1;
    if (dcache[q] >= 0) atomicAdd(&hist[dcache[q] >> 7], 1);
  }
  __syncthreads();
  for (int i = threadIdx.x; i < nb; i += 256) {
    int c = hist[i];
    gbase[i] = c ? atomicAdd(&bcount[i], c) : 0;
  }
  __syncthreads();
  for (int i = threadIdx.x; i < nb; i += 256) hist[i] = 0;  // reuse as rank cursor
  __syncthreads();
  int scache[8];
#pragma unroll
  for (int q = 0; q < 8; ++q) {  // prefetch src indices (independent loads)
    int e = c0 + q * 256 + threadIdx.x;
    scache[q] = (dcache[q] >= 0) ? ei[e] : 0;
  }
#pragma unroll
  for (int q = 0; q < 8; ++q) {
    if (dcache[q] >= 0) {
      int bk = dcache[q] >> 7;
      int r = atomicAdd(&hist[bk], 1);
      pair_buf[bk * CAP + gbase[bk] + r] =
          ((unsigned)scache[q] << 8) | (unsigned)(dcache[q] & 127);
    }
  }
}

// ---------------- K3: GEMM ----------------
// wave: 32 rows x 128 cols. A-frag lane(mr,kg) holds A[m0+mt*16+mr][ks*32+kg*8..+8);
// C/D: col = t*16+mr, row = m0+mt*16+kg*4+r.
// B fragments from LDS (fragment-ordered stage of Wbf, 64 KiB).
__global__ __launch_bounds__(256, 2) void gemm(const float* __restrict__ x,
                                               const unsigned short* __restrict__ Wbf,
                                               unsigned short* __restrict__ hbf,
                                               int N) {
  __shared__ __align__(16) unsigned short Wlds[DOUT * DIN];  // 64 KiB
  // Stage W in fragment order: chunk c = (t*8+ks)*64 + L holds
  // Wbf[(t*16 + (L&15))*DIN + ks*32 + (L>>4)*8 .. +8).
  {
    const int tid = threadIdx.x;
#pragma unroll
    for (int i = 0; i < 16; ++i) {
      int c = i * 256 + tid;                 // chunk 0..4095
      int t = c >> 9, ks = (c >> 6) & 7, L = c & 63;
      const unsigned short* gp = Wbf + ((t * 16 + (L & 15)) * DIN + ks * 32 + (L >> 4) * 8);
      *(bf16x8*)&Wlds[c * 8] = *(const bf16x8*)gp;
    }
  }
  __syncthreads();
  int wid = blockIdx.x * 4 + (threadIdx.x >> 6);
  int m0 = wid * 32;
  if (m0 >= N) return;
  int lane = threadIdx.x & 63;
  int mr = lane & 15, kg = lane >> 4;
  int r0 = m0 + mr;       if (r0 >= N) r0 = N - 1;  // clamp (stores guarded)
  int r1 = m0 + 16 + mr;  if (r1 >= N) r1 = N - 1;
  const float* xr0 = x + (size_t)r0 * DIN + kg * 8;
  const float* xr1 = x + (size_t)r1 * DIN + kg * 8;
  const unsigned short* fb = Wlds + lane * 8;  // lane's fragment base

  f32x4 acc[2][8];
#pragma unroll
  for (int mt = 0; mt < 2; ++mt)
#pragma unroll
    for (int t = 0; t < 8; ++t) acc[mt][t] = (f32x4){0.f, 0.f, 0.f, 0.f};

  float4 p00 = *(const float4*)xr0, p01 = *(const float4*)(xr0 + 4);
  float4 p10 = *(const float4*)xr1, p11 = *(const float4*)(xr1 + 4);
#pragma unroll
  for (int ks = 0; ks < 8; ++ks) {
    bf16x8 a0, a1;
    a0[0] = (short)f2bf(p00.x); a0[1] = (short)f2bf(p00.y);
    a0[2] = (short)f2bf(p00.z); a0[3] = (short)f2bf(p00.w);
    a0[4] = (short)f2bf(p01.x); a0[5] = (short)f2bf(p01.y);
    a0[6] = (short)f2bf(p01.z); a0[7] = (short)f2bf(p01.w);
    a1[0] = (short)f2bf(p10.x); a1[1] = (short)f2bf(p10.y);
    a1[2] = (short)f2bf(p10.z); a1[3] = (short)f2bf(p10.w);
    a1[4] = (short)f2bf(p11.x); a1[5] = (short)f2bf(p11.y);
    a1[6] = (short)f2bf(p11.z); a1[7] = (short)f2bf(p11.w);
    if (ks < 7) {  // prefetch next ks while MFMAs run
      p00 = *(const float4*)(xr0 + (ks + 1) * 32);
      p01 = *(const float4*)(xr0 + (ks + 1) * 32 + 4);
      p10 = *(const float4*)(xr1 + (ks + 1) * 32);
      p11 = *(const float4*)(xr1 + (ks + 1) * 32 + 4);
    }
#pragma unroll
    for (int t = 0; t < 8; ++t) {
      bf16x8 b = *(const bf16x8*)(fb + ((t * 8 + ks) << 9));  // imm offset
      acc[0][t] = __builtin_amdgcn_mfma_f32_16x16x32_bf16(a0, b, acc[0][t], 0, 0, 0);
      acc[1][t] = __builtin_amdgcn_mfma_f32_16x16x32_bf16(a1, b, acc[1][t], 0, 0, 0);
    }
  }
#pragma unroll
  for (int mt = 0; mt < 2; ++mt)
#pragma unroll
    for (int t = 0; t < 8; ++t)
#pragma unroll
      for (int r = 0; r < 4; ++r) {
        int row = m0 + mt * 16 + kg * 4 + r;
        if (row < N) hbf[(size_t)row * DOUT + t * 16 + mr] = f2bf(acc[mt][t][r]);
      }
}

// ---------------- K4: node scores ----------------
__global__ __launch_bounds__(256) void node_scores(const unsigned short* __restrict__ hbf,
                                                   const float* __restrict__ Wa,
                                                   float* __restrict__ a_src,
                                                   float* __restrict__ a_dst,
                                                   int NH) {
  int idx = blockIdx.x * 256 + threadIdx.x;
  if (idx >= NH) return;
  int v = idx >> 3, hh = idx & 7;
  const unsigned short* hp = hbf + (size_t)v * DOUT + hh * 16;
  uint4 p0 = *(const uint4*)hp;
  uint4 p1 = *(const uint4*)(hp + 8);
  float hv[16];
  hv[0] = bflo(p0.x); hv[1] = bfhi(p0.x); hv[2] = bflo(p0.y); hv[3] = bfhi(p0.y);
  hv[4] = bflo(p0.z); hv[5] = bfhi(p0.z); hv[6] = bflo(p0.w); hv[7] = bfhi(p0.w);
  hv[8] = bflo(p1.x); hv[9] = bfhi(p1.x); hv[10] = bflo(p1.y); hv[11] = bfhi(p1.y);
  hv[12] = bflo(p1.z); hv[13] = bfhi(p1.z); hv[14] = bflo(p1.w); hv[15] = bfhi(p1.w);
  float s1 = 0.f, s2 = 0.f;
#pragma unroll
  for (int d = 0; d < 16; ++d) {
    s1 += hv[d] * Wa[d];
    s2 += hv[d] * Wa[16 + d];
  }
  a_src[idx] = s1;
  a_dst[idx] = s2;
}

// ---------------- K5: fused scatter+aggregate, block-local ----------------
// One block (512 thr) per 128-dst bucket. Phase 1: hist+scan+scatter the
// bucket's edges into LDS slist (ushort src, segmented by dst). Phase 2:
// 16-lane group per dst; lane sl covers cols [sl*8,sl*8+8); head = sl>>1.
// acc[8] + den live in registers (den is head-private per lane: both lanes
// of a head pair compute the same e, so no cross-lane reduction needed).
__global__ __launch_bounds__(512) void agg(const unsigned* __restrict__ pair_buf,
                                           const int* __restrict__ bcount,
                                           const unsigned short* __restrict__ hbf,
                                           const float* __restrict__ a_src,
                                           const float* __restrict__ a_dst,
                                           const float* __restrict__ b_att,
                                           float* __restrict__ out, int N) {
  __shared__ int cnt[BKT];
  __shared__ int off[BKT];
  __shared__ int cur[BKT];
  __shared__ int wsum[2];
  __shared__ unsigned short slist[CAP];
  const int t = threadIdx.x;
  const int B = blockIdx.x;
  const int v0 = B * BKT;
  if (t < BKT) cnt[t] = 0;
  __syncthreads();
  const int cntE = min(bcount[B], CAP);
  const unsigned* reg = pair_buf + (size_t)B * CAP;
  // phase 1a: histogram
  for (int i = t; i < cntE; i += 512) atomicAdd(&cnt[reg[i] & 127], 1);
  __syncthreads();
  // phase 1b: exclusive scan over 128 counters (2 waves)
  int val = 0, inc = 0;
  if (t < BKT) {
    val = cnt[t];
    inc = wave_incl_scan(val, t & 63);
    if ((t & 63) == 63) wsum[t >> 6] = inc;
  }
  __syncthreads();
  if (t < BKT) {
    int ex = inc - val + ((t >= 64) ? wsum[0] : 0);
    off[t] = ex;
    cur[t] = ex;
  }
  __syncthreads();
  // phase 1c: scatter into LDS list (re-read reg: L2-hot)
  for (int i = t; i < cntE; i += 512) {
    unsigned p = reg[i];
    int k = atomicAdd(&cur[p & 127], 1);
    slist[k] = (unsigned short)(p >> 8);
  }
  __syncthreads();
  // phase 2: aggregate. group grp owns dsts {grp, grp+32, grp+64, grp+96}.
  const float bb = b_att[0];
  const int grp = t >> 4, sl = t & 15, head = sl >> 1;
  for (int nd = grp; nd < BKT; nd += 32) {
    int v = v0 + nd;
    if (v >= N) continue;
    float ad = a_dst[(size_t)v * H + head] + bb;
    int beg = off[nd], end = cur[nd];
    float a0 = 0, a1 = 0, a2 = 0, a3 = 0, a4 = 0, a5 = 0, a6 = 0, a7 = 0, den = 0;
    int sa = (beg < end) ? slist[beg] : 0;
    int sb = (beg + 1 < end) ? slist[beg + 1] : 0;
    for (int j = beg; j < end; j += 2) {
      int sa2 = (j + 2 < end) ? slist[j + 2] : 0;  // prefetch next pair
      int sb2 = (j + 3 < end) ? slist[j + 3] : 0;
      float asa = a_src[(size_t)sa * H + head];
      float asb = a_src[(size_t)sb * H + head];
      uint4 ua = *(const uint4*)(hbf + (size_t)sa * DOUT + sl * 8);
      uint4 ub = *(const uint4*)(hbf + (size_t)sb * DOUT + sl * 8);
      float ea = __expf(lrelu(asa + ad));
      float eb = (j + 1 < end) ? __expf(lrelu(asb + ad)) : 0.f;
      den += ea + eb;
      a0 += ea * bflo(ua.x) + eb * bflo(ub.x);
      a1 += ea * bfhi(ua.x) + eb * bfhi(ub.x);
      a2 += ea * bflo(ua.y) + eb * bflo(ub.y);
      a3 += ea * bfhi(ua.y) + eb * bfhi(ub.y);
      a4 += ea * bflo(ua.z) + eb * bflo(ub.z);
      a5 += ea * bfhi(ua.z) + eb * bfhi(ub.z);
      a6 += ea * bflo(ua.w) + eb * bflo(ub.w);
      a7 += ea * bfhi(ua.w) + eb * bfhi(ub.w);
      sa = sa2; sb = sb2;
    }
    // self loop + normalize + store
    float es = __expf(lrelu(a_src[(size_t)v * H + head] + ad));
    uint4 u = *(const uint4*)(hbf + (size_t)v * DOUT + sl * 8);
    float inv = 1.0f / (den + es);
    float4 o0 = make_float4((a0 + es * bflo(u.x)) * inv, (a1 + es * bfhi(u.x)) * inv,
                            (a2 + es * bflo(u.y)) * inv, (a3 + es * bfhi(u.y)) * inv);
    float4 o1 = make_float4((a4 + es * bflo(u.z)) * inv, (a5 + es * bfhi(u.z)) * inv,
                            (a6 + es * bflo(u.w)) * inv, (a7 + es * bfhi(u.w)) * inv);
    *(float4*)&out[(size_t)v * DOUT + sl * 8] = o0;
    *(float4*)&out[(size_t)v * DOUT + sl * 8 + 4] = o1;
  }
}

extern "C" void kernel_launch(void* const* d_in, const int* in_sizes, int n_in,
                              void* d_out, int out_size, void* d_ws, size_t ws_size,
                              hipStream_t stream) {
  const float* x     = (const float*)d_in[0];
  const float* W     = (const float*)d_in[1];
  const float* Wa    = (const float*)d_in[2];
  const float* b_att = (const float*)d_in[3];
  const int*   ei    = (const int*)d_in[4];
  const int N  = in_sizes[0] / DIN;
  const int E  = in_sizes[4] / 2;
  const int NB = (N + BKT - 1) / BKT;  // 391 buckets of 128 dst nodes
  float* out = (float*)d_out;

  char* p = (char*)d_ws;
  auto take = [&p](size_t bytes) {
    uintptr_t u = ((uintptr_t)p + 15) & ~(uintptr_t)15;
    p = (char*)(u + bytes);
    return (void*)u;
  };
  unsigned short* hbf = (unsigned short*)take((size_t)N * DOUT * 2);
  unsigned short* Wbf = (unsigned short*)take((size_t)DOUT * DIN * 2);
  float* a_src        = (float*)take((size_t)N * H * 4);
  float* a_dst        = (float*)take((size_t)N * H * 4);
  int* bcount         = (int*)take((size_t)NB * 4);
  unsigned* pair_buf  = (unsigned*)take((size_t)NB * CAP * 4);

  dim3 b256(256);
  const int cw_blocks   = (DOUT * DIN + 255) / 256;       // 128 (covers nb zeroing)
  const int bp_blocks   = (E + CHUNK - 1) / CHUNK;        // 391
  const int gemm_blocks = ((N + 31) / 32 + 3) / 4;        // 391 (4 waves x 32 rows)
  const int ns_blocks   = (N * H + 255) / 256;            // 1563

  conv_w<<<dim3(cw_blocks), b256, 0, stream>>>(W, Wbf, DOUT * DIN, bcount, NB);
  bp<<<dim3(bp_blocks), b256, 0, stream>>>(ei, bcount, pair_buf, E, NB);
  gemm<<<dim3(gemm_blocks), b256, 0, stream>>>(x, Wbf, hbf, N);
  node_scores<<<dim3(ns_blocks), b256, 0, stream>>>(hbf, Wa, a_src, a_dst, N * H);
  agg<<<dim3(NB), dim3(512), 0, stream>>>(pair_buf, bcount, hbf, a_src, a_dst,
                                          b_att, out, N);
}